// Round 3
// baseline (309.342 us; speedup 1.0000x reference)
//
#include <hip/hip_runtime.h>

typedef __attribute__((ext_vector_type(8))) short short8;
typedef __attribute__((ext_vector_type(4))) float float4v;

#define BATCH 16
#define CDIM 2048
#define LDIM 64
#define BSTRIDE (CDIM * LDIM) /* 131072 elems per batch */

__device__ __forceinline__ float bf2f(unsigned short u) {
    unsigned int x = ((unsigned int)u) << 16;
    return __uint_as_float(x);
}
__device__ __forceinline__ unsigned short f2bf(float f) {
    unsigned int x = __float_as_uint(f);
    x += 0x7fffu + ((x >> 16) & 1u); // RNE
    return (unsigned short)(x >> 16);
}

// ---- Fused prepass (one launch): zero out, q*0.125 -> bf16, transpose k,v -> bf16 ----
__global__ __launch_bounds__(256) void prepass_kernel(
    const float* __restrict__ q, const float* __restrict__ k, const float* __restrict__ v,
    float* __restrict__ out, unsigned short* __restrict__ qb,
    unsigned short* __restrict__ kT, unsigned short* __restrict__ vT)
{
    __shared__ float tile[32][33];
    const int sec = blockIdx.x >> 11;
    const int idx = blockIdx.x & 2047;
    const int tid = threadIdx.x;

    if (sec == 0) {
        ((float4v*)out)[idx * 256 + tid] = (float4v){0.f, 0.f, 0.f, 0.f};
    } else if (sec == 1) {
        int i = idx * 256 + tid;
        float4v x = ((const float4v*)q)[i];
        ushort4 o;
        o.x = f2bf(x[0] * 0.125f); o.y = f2bf(x[1] * 0.125f);
        o.z = f2bf(x[2] * 0.125f); o.w = f2bf(x[3] * 0.125f);
        ((ushort4*)qb)[i] = o;
    } else {
        const float* src; unsigned short* dst; int R, C, c0, r0;
        int b = idx >> 7, t = idx & 127;
        if (sec == 2) { R = 64;   C = 2048; c0 = (t >> 1) * 32; r0 = (t & 1) * 32; src = k; dst = kT; }
        else          { R = 2048; C = 64;   c0 = (t & 1) * 32;  r0 = (t >> 1) * 32; src = v; dst = vT; }
        src += (size_t)b * R * C;
        dst += (size_t)b * R * C;
        int tx = tid & 31, ty = tid >> 5;
#pragma unroll
        for (int p = 0; p < 4; p++)
            tile[ty + p * 8][tx] = src[(size_t)(r0 + ty + p * 8) * C + c0 + tx];
        __syncthreads();
#pragma unroll
        for (int p = 0; p < 4; p++)
            dst[(size_t)(c0 + ty + p * 8) * R + r0 + tx] = f2bf(tile[tx][ty + p * 8]);
    }
}

// ---- Dinv kernel: Dinv[m][n] = 1 / sum_b exp(S_b[m][n]) ----
// Grid: dim3(16, 32). Block 512 = 8 waves; wave w -> m-tile (16 rows), block shares n (64 cols).
// No inter-wave communication, no barriers.
__global__ __launch_bounds__(512) void dinv_kernel(
    const unsigned short* __restrict__ qb,
    const unsigned short* __restrict__ kT,
    float* __restrict__ Dinv)
{
    const int tid = threadIdx.x;
    const int w = tid >> 6;
    const int lane = tid & 63;
    const int c = lane & 15;
    const int q = lane >> 4;

    const int m0 = blockIdx.x * 128 + w * 16;
    const int n0 = blockIdx.y * 64;

    float4v Dacc[4];
#pragma unroll
    for (int nt = 0; nt < 4; nt++) Dacc[nt] = (float4v){0.f, 0.f, 0.f, 0.f};

    for (int b = 0; b < BATCH; b++) {
        const unsigned short* qb_b = qb + b * BSTRIDE;
        const unsigned short* kT_b = kT + b * BSTRIDE;
        // B-operand (Q): col=m=c, 8 consecutive i
        short8 Qf0 = *(const short8*)(qb_b + (m0 + c) * LDIM + q * 8);
        short8 Qf1 = *(const short8*)(qb_b + (m0 + c) * LDIM + 32 + q * 8);
#pragma unroll
        for (int nt = 0; nt < 4; nt++) {
            // A-operand (Kt^T): row=n=c, 8 consecutive i
            short8 Af0 = *(const short8*)(kT_b + (n0 + nt * 16 + c) * LDIM + q * 8);
            short8 Af1 = *(const short8*)(kT_b + (n0 + nt * 16 + c) * LDIM + 32 + q * 8);
            float4v d = (float4v){0.f, 0.f, 0.f, 0.f};
            d = __builtin_amdgcn_mfma_f32_16x16x32_bf16(Af0, Qf0, d, 0, 0, 0);
            d = __builtin_amdgcn_mfma_f32_16x16x32_bf16(Af1, Qf1, d, 0, 0, 0);
            // C-frag: col=c=m, row=q*4+r=n (within nt tile)
#pragma unroll
            for (int r = 0; r < 4; r++) Dacc[nt][r] += __expf(d[r]);
        }
    }
#pragma unroll
    for (int nt = 0; nt < 4; nt++) {
        float4v di;
#pragma unroll
        for (int r = 0; r < 4; r++) di[r] = 1.f / Dacc[nt][r];
        *(float4v*)&Dinv[(size_t)(m0 + c) * CDIM + n0 + nt * 16 + q * 4] = di;
    }
}

// ---- Main kernel: out_b = (exp(S_b) * Dinv) @ V_b. Fully per-batch independent. ----
// Grid: 2048 blocks = 16 b x 32 m-groups x 4 n-splits. Block 256 = 4 waves.
// Wave w: m-tile m0=(mg*4+w)*16, batch b, n-range [ns*512, ns*512+512), 16 steps of 32.
// NO __syncthreads in the loop: C->A layout fix-up goes through wave-PRIVATE LDS.
#define EPITCH 40
__global__ __launch_bounds__(256, 4) void attn_main_kernel(
    const unsigned short* __restrict__ qb,
    const unsigned short* __restrict__ kT,
    const unsigned short* __restrict__ vT,
    const float* __restrict__ Dinv,
    float* __restrict__ out)
{
    __shared__ __align__(16) unsigned short E[4][16][EPITCH]; // per-wave private tiles, 5 KB

    const int tid = threadIdx.x;
    const int w = tid >> 6;
    const int lane = tid & 63;
    const int c = lane & 15;
    const int q = lane >> 4;

    const int bx = blockIdx.x;
    const int b = bx & 15;
    const int mg = (bx >> 4) & 31;
    const int ns = bx >> 9;

    const int m0 = (mg * 4 + w) * 16;
    const int nbase = ns * 512;

    const unsigned short* qb_b = qb + b * BSTRIDE;
    const unsigned short* kT_b = kT + b * BSTRIDE;
    const unsigned short* vT_b = vT + b * BSTRIDE;

    // Persistent Q fragments (pre-scaled by 1/8)
    short8 Qf0 = *(const short8*)(qb_b + (m0 + c) * LDIM + q * 8);
    short8 Qf1 = *(const short8*)(qb_b + (m0 + c) * LDIM + 32 + q * 8);

    float4v acc[4];
#pragma unroll
    for (int jt = 0; jt < 4; jt++) acc[jt] = (float4v){0.f, 0.f, 0.f, 0.f};

    for (int st = 0; st < 16; st++) {
        const int n0 = nbase + st * 32;

        // ---- GEMM1: S^T tile (32n x 16m) ----
        float4v Cf[2];
#pragma unroll
        for (int nt = 0; nt < 2; nt++) {
            short8 Af0 = *(const short8*)(kT_b + (n0 + nt * 16 + c) * LDIM + q * 8);
            short8 Af1 = *(const short8*)(kT_b + (n0 + nt * 16 + c) * LDIM + 32 + q * 8);
            float4v d = (float4v){0.f, 0.f, 0.f, 0.f};
            d = __builtin_amdgcn_mfma_f32_16x16x32_bf16(Af0, Qf0, d, 0, 0, 0);
            d = __builtin_amdgcn_mfma_f32_16x16x32_bf16(Af1, Qf1, d, 0, 0, 0);
            Cf[nt] = d;
        }

        // ---- P = exp(S) * Dinv -> bf16 -> private LDS (C-frag layout: m=c, n=nt*16+q*4+r) ----
#pragma unroll
        for (int nt = 0; nt < 2; nt++) {
            float4v dv = *(const float4v*)&Dinv[(size_t)(m0 + c) * CDIM + n0 + nt * 16 + q * 4];
            ushort4 e;
            e.x = f2bf(__expf(Cf[nt][0]) * dv[0]);
            e.y = f2bf(__expf(Cf[nt][1]) * dv[1]);
            e.z = f2bf(__expf(Cf[nt][2]) * dv[2]);
            e.w = f2bf(__expf(Cf[nt][3]) * dv[3]);
            *(ushort4*)&E[w][c][nt * 16 + q * 4] = e;
        }
        // Intra-wave cross-lane exchange: wait LDS writes, forbid reordering. No s_barrier.
        asm volatile("s_waitcnt lgkmcnt(0)" ::: "memory");

        // ---- GEMM2: A-frag P[m=c][n=q*8..+7] = one b128 read ----
        short8 Pf = *(const short8*)&E[w][c][q * 8];
#pragma unroll
        for (int jt = 0; jt < 4; jt++) {
            short8 Vf = *(const short8*)(vT_b + (jt * 16 + c) * CDIM + n0 + q * 8);
            acc[jt] = __builtin_amdgcn_mfma_f32_16x16x32_bf16(Pf, Vf, acc[jt], 0, 0, 0);
        }
    }

    // Epilogue: C/D layout col=c=j, row=q*4+r=m. 4 n-split blocks accumulate via atomics.
#pragma unroll
    for (int jt = 0; jt < 4; jt++)
#pragma unroll
        for (int r = 0; r < 4; r++) {
            int m = m0 + q * 4 + r;
            atomicAdd(&out[((size_t)b * CDIM + m) * LDIM + jt * 16 + c], acc[jt][r]);
        }
}

extern "C" void kernel_launch(void* const* d_in, const int* in_sizes, int n_in,
                              void* d_out, int out_size, void* d_ws, size_t ws_size,
                              hipStream_t stream) {
    const float* q = (const float*)d_in[0];
    const float* k = (const float*)d_in[1];
    const float* v = (const float*)d_in[2];
    float* out = (float*)d_out;

    unsigned short* qb = (unsigned short*)d_ws;        // 4 MB bf16 (pre-scaled by 1/8)
    unsigned short* kT = qb + (size_t)BATCH * BSTRIDE; // 4 MB bf16, [b][n][i]
    unsigned short* vT = kT + (size_t)BATCH * BSTRIDE; // 4 MB bf16, [b][j][n]
    float* Dinv = (float*)(vT + (size_t)BATCH * BSTRIDE); // 16 MB fp32, [m][n]

    prepass_kernel<<<4 * 2048, 256, 0, stream>>>(q, k, v, out, qb, kT, vT);
    dinv_kernel<<<dim3(16, 32), 512, 0, stream>>>(qb, kT, Dinv);
    attn_main_kernel<<<2048, 256, 0, stream>>>(qb, kT, vT, Dinv, out);
}

// Round 4
// 139.624 us; speedup vs baseline: 2.2155x; 2.2155x over previous
//
#include <hip/hip_runtime.h>

typedef __attribute__((ext_vector_type(8))) short short8;
typedef __attribute__((ext_vector_type(4))) float float4v;

#define BATCH 16
#define CDIM 2048
#define LDIM 64
#define BSTRIDE (CDIM * LDIM) /* 131072 elems per batch */

__device__ __forceinline__ float bf2f(unsigned short u) {
    return __uint_as_float(((unsigned int)u) << 16);
}
__device__ __forceinline__ unsigned short f2bf(float f) {
    unsigned int x = __float_as_uint(f);
    x += 0x7fffu + ((x >> 16) & 1u); // RNE
    return (unsigned short)(x >> 16);
}
// Async global->LDS DMA: 16B/lane, lane i lands at lptr + i*16. lptr wave-uniform.
__device__ __forceinline__ void dma16(const void* g, void* l) {
    __builtin_amdgcn_global_load_lds(
        (const __attribute__((address_space(1))) void*)g,
        (__attribute__((address_space(3))) void*)l, 16, 0, 0);
}

// ---- Prepass: zero out; q*0.125 -> swizzled bf16; k,v -> transposed swizzled bf16 tiles ----
// Swizzle rule: within a 128B row of 8 16B-chunks, chunk j stored at j^(row&7).
// vS: V^T tiled by 32-n blocks: [b][nb][j(64)][chunk q^(j&3)][8]; rows 64B (4 chunks).
__global__ __launch_bounds__(256) void prepass_kernel(
    const float* __restrict__ q, const float* __restrict__ k, const float* __restrict__ v,
    float* __restrict__ out, unsigned short* __restrict__ qb,
    unsigned short* __restrict__ kT, unsigned short* __restrict__ vS)
{
    __shared__ float tile[32][33];
    const int bx = blockIdx.x;
    const int tid = threadIdx.x;
    if (bx < 2048) {
        ((float4v*)out)[bx * 256 + tid] = (float4v){0.f, 0.f, 0.f, 0.f};
    } else if (bx < 3072) {
        int i = (bx - 2048) * 256 + tid; // one 16B-chunk (8 bf16) per thread
        const float4v* src = (const float4v*)q + (size_t)i * 2;
        float4v x0 = src[0], x1 = src[1];
        unsigned int u0 = f2bf(x0[0] * 0.125f) | ((unsigned)f2bf(x0[1] * 0.125f) << 16);
        unsigned int u1 = f2bf(x0[2] * 0.125f) | ((unsigned)f2bf(x0[3] * 0.125f) << 16);
        unsigned int u2 = f2bf(x1[0] * 0.125f) | ((unsigned)f2bf(x1[1] * 0.125f) << 16);
        unsigned int u3 = f2bf(x1[2] * 0.125f) | ((unsigned)f2bf(x1[3] * 0.125f) << 16);
        int b = i >> 14, r = i & 16383, m = r >> 3, j = r & 7;
        *(uint4*)(qb + (size_t)b * BSTRIDE + m * 64 + (j ^ (m & 7)) * 8) =
            make_uint4(u0, u1, u2, u3);
    } else if (bx < 5120) { // k (64i x 2048n) -> kT[b][n][i] swizzled
        int idx = bx - 3072; int b = idx >> 7, t = idx & 127;
        int c0 = (t >> 1) * 32, r0 = (t & 1) * 32; // c0: n, r0: i
        const float* src = k + (size_t)b * BSTRIDE;
        unsigned short* dst = kT + (size_t)b * BSTRIDE;
        int tx = tid & 31, ty = tid >> 5;
#pragma unroll
        for (int p = 0; p < 4; p++)
            tile[ty + p * 8][tx] = src[(size_t)(r0 + ty + p * 8) * 2048 + c0 + tx];
        __syncthreads();
#pragma unroll
        for (int p = 0; p < 4; p++) {
            int n = c0 + ty + p * 8, ic = r0 + tx, j = ic >> 3;
            dst[(size_t)n * 64 + (j ^ (n & 7)) * 8 + (tx & 7)] = f2bf(tile[tx][ty + p * 8]);
        }
    } else { // v (2048n x 64j) -> vS[b][nb][j][swz]
        int idx = bx - 5120; int b = idx >> 7, t = idx & 127;
        int c0 = (t & 1) * 32, r0 = (t >> 1) * 32; // c0: j, r0: n
        const float* src = v + (size_t)b * BSTRIDE;
        unsigned short* dst = vS + (size_t)b * BSTRIDE;
        int tx = tid & 31, ty = tid >> 5;
#pragma unroll
        for (int p = 0; p < 4; p++)
            tile[ty + p * 8][tx] = src[(size_t)(r0 + ty + p * 8) * 64 + c0 + tx];
        __syncthreads();
#pragma unroll
        for (int p = 0; p < 4; p++) {
            int j = c0 + ty + p * 8, nb = r0 >> 5, qc = tx >> 3;
            dst[(size_t)nb * 2048 + j * 32 + (qc ^ (j & 3)) * 8 + (tx & 7)] =
                f2bf(tile[tx][ty + p * 8]);
        }
    }
}

// ---- dinv: Dt tile(T = mt*64 + nstep) of 128m x 32n bf16 1/D, row-chunk-swizzled ----
// Grid 512 = 16 mt x 32 ng. Block 256 = 4 waves; wave w: m-rows w*32+ms*16+c.
__global__ __launch_bounds__(256, 2) void dinv_kernel(
    const unsigned short* __restrict__ qb, const unsigned short* __restrict__ kT,
    unsigned short* __restrict__ Dt)
{
    __shared__ unsigned short Sq[8192]; // 16KB: 128 rows x 64
    __shared__ unsigned short Sk[4096]; // 8KB : 64 rows x 64
    const int tid = threadIdx.x, w = tid >> 6, lane = tid & 63;
    const int c = lane & 15, q = lane >> 4;
    const int mt = blockIdx.x & 15, ng = blockIdx.x >> 4;
    const int m0 = mt * 128, n0 = ng * 64;

    float4v Dacc[2][4];
#pragma unroll
    for (int ms = 0; ms < 2; ms++)
#pragma unroll
        for (int nt = 0; nt < 4; nt++) Dacc[ms][nt] = (float4v){0.f, 0.f, 0.f, 0.f};

    for (int b = 0; b < BATCH; b++) {
        __syncthreads();
        const char* qg = (const char*)(qb + (size_t)b * BSTRIDE + (size_t)m0 * 64);
        const char* kg = (const char*)(kT + (size_t)b * BSTRIDE + (size_t)n0 * 64);
#pragma unroll
        for (int kk = 0; kk < 4; kk++)
            dma16(qg + (w * 4 + kk) * 1024 + lane * 16, (char*)Sq + (w * 4 + kk) * 1024);
        dma16(kg + (w * 2 + 0) * 1024 + lane * 16, (char*)Sk + (w * 2 + 0) * 1024);
        dma16(kg + (w * 2 + 1) * 1024 + lane * 16, (char*)Sk + (w * 2 + 1) * 1024);
        asm volatile("s_waitcnt vmcnt(0)" ::: "memory");
        __syncthreads();

        short8 Qf[2][2];
#pragma unroll
        for (int ms = 0; ms < 2; ms++)
#pragma unroll
            for (int h = 0; h < 2; h++)
                Qf[ms][h] = *(const short8*)&Sq[(w * 32 + ms * 16 + c) * 64 +
                                                ((h * 4 + q) ^ (c & 7)) * 8];
#pragma unroll
        for (int nt = 0; nt < 4; nt++) {
            short8 A0 = *(const short8*)&Sk[(nt * 16 + c) * 64 + (q ^ (c & 7)) * 8];
            short8 A1 = *(const short8*)&Sk[(nt * 16 + c) * 64 + ((4 + q) ^ (c & 7)) * 8];
#pragma unroll
            for (int ms = 0; ms < 2; ms++) {
                float4v d = (float4v){0.f, 0.f, 0.f, 0.f};
                d = __builtin_amdgcn_mfma_f32_16x16x32_bf16(A0, Qf[ms][0], d, 0, 0, 0);
                d = __builtin_amdgcn_mfma_f32_16x16x32_bf16(A1, Qf[ms][1], d, 0, 0, 0);
#pragma unroll
                for (int r = 0; r < 4; r++) Dacc[ms][nt][r] += __expf(d[r]);
            }
        }
    }
#pragma unroll
    for (int ms = 0; ms < 2; ms++)
#pragma unroll
        for (int nt = 0; nt < 4; nt++) {
            int m_local = w * 32 + ms * 16 + c;
            int T = mt * 64 + ng * 2 + (nt >> 1);
            int j = (nt & 1) * 4 + q;
            ushort4 o;
#pragma unroll
            for (int r = 0; r < 4; r++) o[r] = f2bf(1.f / Dacc[ms][nt][r]);
            *(ushort4*)&Dt[(size_t)T * 4096 + m_local * 32 + (j ^ (c & 7)) * 4] = o;
        }
}

// ---- Main: out_b += (exp(S_b)*Dinv) @ V_b. Grid 1024 = 16b x 16mt x 4ns; 4 blocks/CU. ----
__global__ __launch_bounds__(256, 4) void attn_main_kernel(
    const unsigned short* __restrict__ qb, const unsigned short* __restrict__ kT,
    const unsigned short* __restrict__ vS, const unsigned short* __restrict__ Dt,
    float* __restrict__ out)
{
    __shared__ unsigned short Sk[2048];        // 4KB: 32 n-rows x 64
    __shared__ unsigned short Sv[2048];        // 4KB: 64 j-rows x 32
    __shared__ unsigned short Sd[4096];        // 8KB: 128 m-rows x 32 (bf16 1/D)
    __shared__ unsigned short Ep[4][2][16][40]; // 10KB wave-private P tiles

    const int tid = threadIdx.x, w = tid >> 6, lane = tid & 63;
    const int c = lane & 15, q = lane >> 4;
    const int b = blockIdx.x & 15, mt = (blockIdx.x >> 4) & 15, ns = blockIdx.x >> 8;
    const int m0 = mt * 128, nbase = ns * 512;

    const unsigned short* qb_b = qb + (size_t)b * BSTRIDE;
    const char* kbase = (const char*)(kT + (size_t)b * BSTRIDE);
    const char* vbase = (const char*)(vS + (size_t)b * BSTRIDE);

    short8 Qf[2][2];
#pragma unroll
    for (int ms = 0; ms < 2; ms++)
#pragma unroll
        for (int h = 0; h < 2; h++)
            Qf[ms][h] = *(const short8*)(qb_b + (m0 + w * 32 + ms * 16 + c) * 64 +
                                         ((h * 4 + q) ^ (c & 7)) * 8);
    float4v acc[2][4];
#pragma unroll
    for (int ms = 0; ms < 2; ms++)
#pragma unroll
        for (int jt = 0; jt < 4; jt++) acc[ms][jt] = (float4v){0.f, 0.f, 0.f, 0.f};

    for (int st = 0; st < 16; st++) {
        const int n0 = nbase + st * 32;
        const int T = mt * 64 + ns * 16 + st;
        __syncthreads(); // previous step's stage consumers done
        dma16(kbase + (size_t)n0 * 128 + w * 1024 + lane * 16, (char*)Sk + w * 1024);
        dma16(vbase + (size_t)(ns * 16 + st) * 4096 + w * 1024 + lane * 16,
              (char*)Sv + w * 1024);
        dma16((const char*)Dt + (size_t)T * 8192 + w * 1024 + lane * 16,
              (char*)Sd + w * 1024);
        dma16((const char*)Dt + (size_t)T * 8192 + (w + 4) * 1024 + lane * 16,
              (char*)Sd + (w + 4) * 1024);
        asm volatile("s_waitcnt vmcnt(0)" ::: "memory");
        __syncthreads(); // stage landed

        // GEMM1 (S^T) + exp*Dinv -> P (bf16) into wave-private LDS
#pragma unroll
        for (int nt = 0; nt < 2; nt++) {
            short8 A0 = *(const short8*)&Sk[(nt * 16 + c) * 64 + (q ^ (c & 7)) * 8];
            short8 A1 = *(const short8*)&Sk[(nt * 16 + c) * 64 + ((4 + q) ^ (c & 7)) * 8];
#pragma unroll
            for (int ms = 0; ms < 2; ms++) {
                float4v d = (float4v){0.f, 0.f, 0.f, 0.f};
                d = __builtin_amdgcn_mfma_f32_16x16x32_bf16(A0, Qf[ms][0], d, 0, 0, 0);
                d = __builtin_amdgcn_mfma_f32_16x16x32_bf16(A1, Qf[ms][1], d, 0, 0, 0);
                uint2 du = *(const uint2*)&Sd[(w * 32 + ms * 16 + c) * 32 +
                                              (((nt * 4 + q) ^ (c & 7)) * 4)];
                float d0 = __uint_as_float(du.x << 16);
                float d1 = __uint_as_float(du.x & 0xffff0000u);
                float d2 = __uint_as_float(du.y << 16);
                float d3 = __uint_as_float(du.y & 0xffff0000u);
                ushort4 e;
                e.x = f2bf(__expf(d[0]) * d0);
                e.y = f2bf(__expf(d[1]) * d1);
                e.z = f2bf(__expf(d[2]) * d2);
                e.w = f2bf(__expf(d[3]) * d3);
                *(ushort4*)&Ep[w][ms][c][nt * 16 + q * 4] = e;
            }
        }
        asm volatile("s_waitcnt lgkmcnt(0)" ::: "memory"); // intra-wave P exchange

        // GEMM2: acc += P @ V
#pragma unroll
        for (int ms = 0; ms < 2; ms++) {
            short8 Pf = *(const short8*)&Ep[w][ms][c][q * 8];
#pragma unroll
            for (int jt = 0; jt < 4; jt++) {
                short8 Vf = *(const short8*)&Sv[(jt * 16 + c) * 32 + (q ^ (c & 3)) * 8];
                acc[ms][jt] = __builtin_amdgcn_mfma_f32_16x16x32_bf16(Pf, Vf, acc[ms][jt], 0, 0, 0);
            }
        }
    }

    // Epilogue: C/D col=c=j, row=q*4+r=m. 4 ns-blocks accumulate via atomics.
#pragma unroll
    for (int ms = 0; ms < 2; ms++)
#pragma unroll
        for (int jt = 0; jt < 4; jt++)
#pragma unroll
            for (int r = 0; r < 4; r++) {
                int m = m0 + w * 32 + ms * 16 + q * 4 + r;
                atomicAdd(&out[((size_t)b * CDIM + m) * LDIM + jt * 16 + c], acc[ms][jt][r]);
            }
}

extern "C" void kernel_launch(void* const* d_in, const int* in_sizes, int n_in,
                              void* d_out, int out_size, void* d_ws, size_t ws_size,
                              hipStream_t stream) {
    const float* q = (const float*)d_in[0];
    const float* k = (const float*)d_in[1];
    const float* v = (const float*)d_in[2];
    float* out = (float*)d_out;

    unsigned short* qb = (unsigned short*)d_ws;        // 4 MB bf16 swizzled (q*0.125)
    unsigned short* kT = qb + (size_t)BATCH * BSTRIDE; // 4 MB bf16 swizzled [b][n][i]
    unsigned short* vS = kT + (size_t)BATCH * BSTRIDE; // 4 MB bf16 tiled [b][nb][j][nn]
    unsigned short* Dt = vS + (size_t)BATCH * BSTRIDE; // 8 MB bf16 1/D tiles

    prepass_kernel<<<7168, 256, 0, stream>>>(q, k, v, out, qb, kT, vS);
    dinv_kernel<<<512, 256, 0, stream>>>(qb, kT, Dt);
    attn_main_kernel<<<1024, 256, 0, stream>>>(qb, kT, vS, Dt, out);
}